// Round 1
// baseline (1435.816 us; speedup 1.0000x reference)
//
#include <hip/hip_runtime.h>

// Problem constants (from reference setup_inputs)
#define Bv 4
#define Sv 4096
#define Dv 1024
#define Hv 16
#define HDv 64
#define Ov 64
#define Cv 64              // chunk length
#define NCv (Sv / Cv)      // 64 chunks
#define BHv (Bv * Hv)      // 64 (b,h) pairs
#define STSZ (Ov * Ov + Ov) // 4160 floats per chunk state (KtV + ksum)

__device__ __forceinline__ float elu1(float a) {
  // phi(u) = elu(u) + 1  ==  u+1 (u>0)  else exp(u)
  return a > 0.f ? a + 1.f : expf(a);
}

// ---------------------------------------------------------------------------
// Kernel 1: per-(b,h,chunk) state summary:  KtV[e][o] = sum_t k[t][e] v[t][o],
//           z[e] = sum_t k[t][e]
// ---------------------------------------------------------------------------
__global__ __launch_bounds__(256) void k_chunk_state(
    const float* __restrict__ x, const float* __restrict__ Wk,
    const float* __restrict__ Wv, float* __restrict__ states)
{
  __shared__ float xs[Cv][HDv];
  __shared__ float ks[Cv][65];
  __shared__ float vs[Cv][65];
  const int tid = threadIdx.x;
  const int blk = blockIdx.x;
  const int c = blk % NCv, bh = blk / NCv, h = bh % Hv, b = bh / Hv;

  const float* xp = x + ((size_t)b * Sv + (size_t)c * Cv) * Dv + (size_t)h * HDv;
  for (int i = tid; i < Cv * HDv; i += 256) {
    int t = i >> 6, d = i & 63;
    xs[t][d] = xp[(size_t)t * Dv + d];  // 256B contiguous per wave
  }
  __syncthreads();

  const int o = tid & 63, t0 = tid >> 6;

  { // k pass: register-blocked over 16 rows, W streamed once
    const float* w = Wk + (size_t)h * HDv * Ov;
    float acc[16];
#pragma unroll
    for (int i = 0; i < 16; ++i) acc[i] = 0.f;
    for (int d = 0; d < HDv; ++d) {
      float wv = w[d * Ov + o];
#pragma unroll
      for (int i = 0; i < 16; ++i) acc[i] += xs[t0 + 4 * i][d] * wv;
    }
#pragma unroll
    for (int i = 0; i < 16; ++i) ks[t0 + 4 * i][o] = elu1(acc[i]);
  }
  { // v pass
    const float* w = Wv + (size_t)h * HDv * Ov;
    float acc[16];
#pragma unroll
    for (int i = 0; i < 16; ++i) acc[i] = 0.f;
    for (int d = 0; d < HDv; ++d) {
      float wv = w[d * Ov + o];
#pragma unroll
      for (int i = 0; i < 16; ++i) acc[i] += xs[t0 + 4 * i][d] * wv;
    }
#pragma unroll
    for (int i = 0; i < 16; ++i) vs[t0 + 4 * i][o] = acc[i];
  }
  __syncthreads();

  float* st = states + (size_t)blk * STSZ;
#pragma unroll
  for (int i = 0; i < 16; ++i) {
    int e = t0 + 4 * i;            // wave-uniform -> ks broadcast read
    float a = 0.f;
    for (int t = 0; t < Cv; ++t) a += ks[t][e] * vs[t][o];
    st[e * Ov + o] = a;
  }
  if (tid < 64) {
    float z = 0.f;
    for (int t = 0; t < Cv; ++t) z += ks[t][tid];  // stride-65: conflict-free
    st[Ov * Ov + tid] = z;
  }
}

// ---------------------------------------------------------------------------
// Kernel 2: exclusive prefix-sum of chunk states along the chunk axis.
// Element-parallel (each element's carry chain independent) -> no barriers.
// ---------------------------------------------------------------------------
__global__ __launch_bounds__(1024) void k_prefix(float* __restrict__ states)
{
  const int bh = blockIdx.x, tid = threadIdx.x;
  float carry[5];
#pragma unroll
  for (int j = 0; j < 5; ++j) carry[j] = 0.f;
  float* base = states + (size_t)bh * NCv * STSZ;
  for (int c = 0; c < NCv; ++c) {
    float* st = base + (size_t)c * STSZ;
#pragma unroll
    for (int j = 0; j < 5; ++j) {
      int i = tid + j * 1024;
      if (i < STSZ) {
        float v = st[i];
        st[i] = carry[j];
        carry[j] += v;
      }
    }
  }
}

// ---------------------------------------------------------------------------
// Kernel 3: per-(b,h,chunk) output:
//   A[t][s] = q_t . k_s  (s<=t, else 0)
//   num[t][o] = q_t . Sprev[:,o] + sum_s A[t][s] v[s][o]
//   den[t]    = q_t . zprev + rowsum(A[t])
//   y[t][o]   = num/(den+eps)
// LDS overlays: buf0 = xs then A;  ksp = ks then (Sprev|zprev)
// ---------------------------------------------------------------------------
__global__ __launch_bounds__(256) void k_chunk_out(
    const float* __restrict__ x, const float* __restrict__ Wq,
    const float* __restrict__ Wk, const float* __restrict__ Wv,
    const float* __restrict__ states, float* __restrict__ y)
{
  __shared__ float buf0[Cv][65];   // xs, later A
  __shared__ float qs[Cv][65];
  __shared__ float ksp[Cv][65];    // ks, later Sprev(4096)+zprev(64) = 4160
  __shared__ float vs[Cv][65];
  const int tid = threadIdx.x;
  const int blk = blockIdx.x;
  const int c = blk % NCv, bh = blk / NCv, h = bh % Hv, b = bh / Hv;

  // Early-issue the prev-state load into registers (overlaps with compute).
  const float* st = states + (size_t)blk * STSZ;
  float spreg[17];
#pragma unroll
  for (int j = 0; j < 17; ++j) {
    int i = tid + j * 256;
    spreg[j] = (i < STSZ) ? st[i] : 0.f;
  }

  const float* xp = x + ((size_t)b * Sv + (size_t)c * Cv) * Dv + (size_t)h * HDv;
  for (int i = tid; i < Cv * HDv; i += 256) {
    int t = i >> 6, d = i & 63;
    buf0[t][d] = xp[(size_t)t * Dv + d];
  }
  __syncthreads();

  const int o = tid & 63, t0 = tid >> 6;

  { // q pass
    const float* w = Wq + (size_t)h * HDv * Ov;
    float acc[16];
#pragma unroll
    for (int i = 0; i < 16; ++i) acc[i] = 0.f;
    for (int d = 0; d < HDv; ++d) {
      float wv = w[d * Ov + o];
#pragma unroll
      for (int i = 0; i < 16; ++i) acc[i] += buf0[t0 + 4 * i][d] * wv;
    }
#pragma unroll
    for (int i = 0; i < 16; ++i) qs[t0 + 4 * i][o] = elu1(acc[i]);
  }
  { // k pass
    const float* w = Wk + (size_t)h * HDv * Ov;
    float acc[16];
#pragma unroll
    for (int i = 0; i < 16; ++i) acc[i] = 0.f;
    for (int d = 0; d < HDv; ++d) {
      float wv = w[d * Ov + o];
#pragma unroll
      for (int i = 0; i < 16; ++i) acc[i] += buf0[t0 + 4 * i][d] * wv;
    }
#pragma unroll
    for (int i = 0; i < 16; ++i) ksp[t0 + 4 * i][o] = elu1(acc[i]);
  }
  { // v pass
    const float* w = Wv + (size_t)h * HDv * Ov;
    float acc[16];
#pragma unroll
    for (int i = 0; i < 16; ++i) acc[i] = 0.f;
    for (int d = 0; d < HDv; ++d) {
      float wv = w[d * Ov + o];
#pragma unroll
      for (int i = 0; i < 16; ++i) acc[i] += buf0[t0 + 4 * i][d] * wv;
    }
#pragma unroll
    for (int i = 0; i < 16; ++i) vs[t0 + 4 * i][o] = acc[i];
  }
  __syncthreads();

  { // A = causal QK^T into buf0 (xs dead now)
    const int s = o;               // lane
#pragma unroll
    for (int i = 0; i < 16; ++i) {
      int t = t0 + 4 * i;          // wave-uniform
      float a = 0.f;
      if (s <= t) {
        for (int d = 0; d < HDv; ++d) a += qs[t][d] * ksp[s][d];  // bcast / stride-65
      }
      buf0[t][s] = a;
    }
  }
  __syncthreads();

  { // overwrite ksp with Sprev|zprev (ks dead now)
    float* spf = &ksp[0][0];
#pragma unroll
    for (int j = 0; j < 17; ++j) {
      int i = tid + j * 256;
      if (i < STSZ) spf[i] = spreg[j];
    }
  }
  __syncthreads();

  const float* spf = &ksp[0][0];
  float* yp = y + (((size_t)b * Sv + (size_t)c * Cv) * Hv + h) * Ov;
#pragma unroll
  for (int i = 0; i < 16; ++i) {
    int t = t0 + 4 * i;            // wave-uniform -> inner bounds uniform
    float num = 0.f, den = 0.f;
    for (int e = 0; e < Ov; ++e) {
      float qv = qs[t][e];                 // broadcast
      num += qv * spf[e * Ov + o];         // lanes consecutive
      den += qv * spf[Ov * Ov + e];        // broadcast
    }
    for (int ss = 0; ss <= t; ++ss) {
      float a = buf0[t][ss];               // broadcast
      num += a * vs[ss][o];                // lanes consecutive
      den += a;
    }
    yp[(size_t)t * (Hv * Ov) + o] = num / (den + 1e-6f);
  }
}

// ---------------------------------------------------------------------------
// Kernel 4: out[row][o2] = sum_d y[row][d] * Wp[d][o2]   (row = b*S+s)
// 16 rows per block; Wp tiled through LDS (4 x 256x64 tiles)
// ---------------------------------------------------------------------------
__global__ __launch_bounds__(256) void k_proj(
    const float* __restrict__ y, const float* __restrict__ Wp,
    float* __restrict__ out)
{
  __shared__ float ys[16][1024];  // 64 KB
  __shared__ float wp[256][64];   // 64 KB
  const int tid = threadIdx.x;
  const size_t row0 = (size_t)blockIdx.x * 16;

  const float* yp = y + row0 * 1024;
  for (int i = tid; i < 16 * 1024; i += 256)
    (&ys[0][0])[i] = yp[i];

  const int o = tid & 63;
  const int w = tid >> 6;  // wave id, rows w*4 .. w*4+3
  float acc[4] = {0.f, 0.f, 0.f, 0.f};

  for (int dt = 0; dt < 4; ++dt) {
    __syncthreads();               // ys ready (dt=0) / prev tile consumed
    for (int i = tid; i < 256 * 64; i += 256)
      (&wp[0][0])[i] = Wp[dt * 256 * 64 + i];
    __syncthreads();
    for (int d = 0; d < 256; ++d) {
      float wv = wp[d][o];
#pragma unroll
      for (int r = 0; r < 4; ++r)
        acc[r] += ys[w * 4 + r][dt * 256 + d] * wv;
    }
  }
#pragma unroll
  for (int r = 0; r < 4; ++r)
    out[(row0 + (size_t)w * 4 + r) * 64 + o] = acc[r];
}

// ---------------------------------------------------------------------------
extern "C" void kernel_launch(void* const* d_in, const int* in_sizes, int n_in,
                              void* d_out, int out_size, void* d_ws, size_t ws_size,
                              hipStream_t stream)
{
  const float* x  = (const float*)d_in[0];
  const float* Wq = (const float*)d_in[1];
  const float* Wk = (const float*)d_in[2];
  const float* Wv = (const float*)d_in[3];
  const float* Wp = (const float*)d_in[4];
  float* out = (float*)d_out;

  // workspace layout: states [BH*NC*4160] f32, then y [B*S*H*O] f32  (~129 MB)
  float* states = (float*)d_ws;
  float* y = states + (size_t)BHv * NCv * STSZ;

  hipLaunchKernelGGL(k_chunk_state, dim3(BHv * NCv), dim3(256), 0, stream,
                     x, Wk, Wv, states);
  hipLaunchKernelGGL(k_prefix, dim3(BHv), dim3(1024), 0, stream, states);
  hipLaunchKernelGGL(k_chunk_out, dim3(BHv * NCv), dim3(256), 0, stream,
                     x, Wq, Wk, Wv, states, y);
  hipLaunchKernelGGL(k_proj, dim3((Bv * Sv) / 16), dim3(256), 0, stream,
                     y, Wp, out);
}

// Round 2
// 202.465 us; speedup vs baseline: 7.0917x; 7.0917x over previous
//
#include <hip/hip_runtime.h>

// Problem constants
#define Bv 4
#define Sv 4096
#define Dv 1024
#define Hv 16
#define Ov 64
#define NCv 64
#define BHv 64
#define STSZ (64 * 64 + 64)   // 4160 fp32 per chunk state

typedef __attribute__((ext_vector_type(8))) short bf16x8;
typedef __attribute__((ext_vector_type(4))) float f32x4;
#define MFMA(a, b, c) __builtin_amdgcn_mfma_f32_16x16x32_bf16(a, b, c, 0, 0, 0)

__device__ __forceinline__ unsigned short f2b(float f) {
  union { float f; unsigned u; } v; v.f = f;
  unsigned r = v.u + 0x7fffu + ((v.u >> 16) & 1u);   // RNE
  return (unsigned short)(r >> 16);
}
__device__ __forceinline__ float b2f(unsigned short u) {
  union { unsigned u; float f; } v; v.u = ((unsigned)u) << 16; return v.f;
}
__device__ __forceinline__ float elu1(float a) {
  return a > 0.f ? a + 1.f : expf(a);
}
__device__ __forceinline__ f32x4 zero4() {
  f32x4 v; v[0] = 0.f; v[1] = 0.f; v[2] = 0.f; v[3] = 0.f; return v;
}

// ---------------------------------------------------------------------------
// K0: Wp [1024][64] f32 -> WpT [64][1024] bf16
// ---------------------------------------------------------------------------
__global__ __launch_bounds__(256) void k_prep(
    const float* __restrict__ Wp, unsigned short* __restrict__ wpT)
{
#pragma unroll
  for (int j = 0; j < 4; ++j) {
    int idx = blockIdx.x * 1024 + threadIdx.x + j * 256;  // = d*64+o
    int d = idx >> 6, o = idx & 63;
    wpT[o * 1024 + d] = f2b(Wp[idx]);
  }
}

// ---------------------------------------------------------------------------
// K1: per (bh,chunk): K=elu1(x Wk), V=x Wv; states = {K^T V [64x64], colsum K}
// ---------------------------------------------------------------------------
__global__ __launch_bounds__(256) void k_chunk_state(
    const float* __restrict__ x, const float* __restrict__ Wk,
    const float* __restrict__ Wv, float* __restrict__ states)
{
  __shared__ __align__(16) unsigned short xs[64][72];
  __shared__ __align__(16) unsigned short wkT[64][72];
  __shared__ __align__(16) unsigned short wvT[64][72];
  __shared__ __align__(16) unsigned short kt[64][72];   // K^T: kt[e][t]
  __shared__ __align__(16) unsigned short vt[64][72];   // V^T: vt[o][t]
  __shared__ float zp4[4][64];

  const int tid = threadIdx.x;
  const int blk = blockIdx.x;
  const int c = blk & 63, bh = blk >> 6, h = bh & 15, b = bh >> 4;
  const int lane = tid & 63, w = tid >> 6;
  const int ll = lane & 15, hl = lane >> 4;

  const float* xp = x + ((size_t)(b * Sv + c * 64)) * Dv + h * 64;
  const float* wkp = Wk + h * 4096;
  const float* wvp = Wv + h * 4096;
  for (int i = tid; i < 4096; i += 256) {
    int r = i >> 6, d = i & 63;
    xs[r][d] = f2b(xp[(size_t)r * Dv + d]);
    wkT[d][r] = f2b(wkp[i]);   // Wk[h][r][d] -> wkT[o=d][dd=r]
    wvT[d][r] = f2b(wvp[i]);
  }
  __syncthreads();

  const bf16x8 xa0 = *(const bf16x8*)&xs[w * 16 + ll][hl * 8];
  const bf16x8 xa1 = *(const bf16x8*)&xs[w * 16 + ll][32 + hl * 8];

  f32x4 acc[4];
  // K = elu1(x Wk) -> kt[e][t]
#pragma unroll
  for (int ct = 0; ct < 4; ++ct) {
    acc[ct] = zero4();
    bf16x8 b0 = *(const bf16x8*)&wkT[ct * 16 + ll][hl * 8];
    bf16x8 b1 = *(const bf16x8*)&wkT[ct * 16 + ll][32 + hl * 8];
    acc[ct] = MFMA(xa0, b0, acc[ct]);
    acc[ct] = MFMA(xa1, b1, acc[ct]);
  }
#pragma unroll
  for (int ct = 0; ct < 4; ++ct)
#pragma unroll
    for (int r = 0; r < 4; ++r)
      kt[ct * 16 + ll][w * 16 + hl * 4 + r] = f2b(elu1(acc[ct][r]));
  // V = x Wv -> vt[o][t]
#pragma unroll
  for (int ct = 0; ct < 4; ++ct) {
    acc[ct] = zero4();
    bf16x8 b0 = *(const bf16x8*)&wvT[ct * 16 + ll][hl * 8];
    bf16x8 b1 = *(const bf16x8*)&wvT[ct * 16 + ll][32 + hl * 8];
    acc[ct] = MFMA(xa0, b0, acc[ct]);
    acc[ct] = MFMA(xa1, b1, acc[ct]);
  }
#pragma unroll
  for (int ct = 0; ct < 4; ++ct)
#pragma unroll
    for (int r = 0; r < 4; ++r)
      vt[ct * 16 + ll][w * 16 + hl * 4 + r] = f2b(acc[ct][r]);
  __syncthreads();

  // KtV[e][o] = sum_t kt[e][t] * V[t][o]
  const bf16x8 ka0 = *(const bf16x8*)&kt[w * 16 + ll][hl * 8];
  const bf16x8 ka1 = *(const bf16x8*)&kt[w * 16 + ll][32 + hl * 8];
  float* st = states + (size_t)blk * STSZ;
#pragma unroll
  for (int ct = 0; ct < 4; ++ct) {
    f32x4 s4 = zero4();
    bf16x8 b0 = *(const bf16x8*)&vt[ct * 16 + ll][hl * 8];
    bf16x8 b1 = *(const bf16x8*)&vt[ct * 16 + ll][32 + hl * 8];
    s4 = MFMA(ka0, b0, s4);
    s4 = MFMA(ka1, b1, s4);
#pragma unroll
    for (int r = 0; r < 4; ++r)
      st[(w * 16 + hl * 4 + r) * 64 + ct * 16 + ll] = s4[r];
  }
  // z[e] = sum_t kt[e][t]
  {
    int e = tid & 63, p = tid >> 6;
    float zs = 0.f;
#pragma unroll
    for (int j = 0; j < 16; ++j) zs += b2f(kt[e][p * 16 + j]);
    zp4[p][e] = zs;
  }
  __syncthreads();
  if (tid < 64)
    st[4096 + tid] = zp4[0][tid] + zp4[1][tid] + zp4[2][tid] + zp4[3][tid];
}

// ---------------------------------------------------------------------------
// K2: exclusive prefix over chunks (element-parallel, fp32)
// ---------------------------------------------------------------------------
__global__ __launch_bounds__(1024) void k_prefix(float* __restrict__ states)
{
  const int bh = blockIdx.x, tid = threadIdx.x;
  float carry[5];
#pragma unroll
  for (int j = 0; j < 5; ++j) carry[j] = 0.f;
  float* base = states + (size_t)bh * NCv * STSZ;
  for (int c = 0; c < NCv; ++c) {
    float* st = base + (size_t)c * STSZ;
#pragma unroll
    for (int j = 0; j < 5; ++j) {
      int i = tid + j * 1024;
      if (i < STSZ) {
        float v = st[i];
        st[i] = carry[j];
        carry[j] += v;
      }
    }
  }
}

// ---------------------------------------------------------------------------
// K3: per (bh,chunk): y = (Q Sprev + tril(Q K^T) V) / (Q zprev + rowsum + eps)
// ---------------------------------------------------------------------------
__global__ __launch_bounds__(256) void k_chunk_out(
    const float* __restrict__ x, const float* __restrict__ Wq,
    const float* __restrict__ Wk, const float* __restrict__ Wv,
    const float* __restrict__ states, unsigned short* __restrict__ y)
{
  __shared__ __align__(16) unsigned char smem[64512];
  auto xs   = (unsigned short(*)[72])(smem);            // phase2: As
  auto wqT  = (unsigned short(*)[72])(smem + 9216);     // phase2: SpT
  auto wkT  = (unsigned short(*)[72])(smem + 18432);    // phase2: denA/den0p/zp
  float* denA  = (float*)(smem + 18432);                // [64]
  float* den0p = (float*)(smem + 18432 + 256);          // [4][64]
  float* zp    = (float*)(smem + 18432 + 256 + 1024);   // [64]
  auto wvT  = (unsigned short(*)[72])(smem + 27648);
  auto qrow = (unsigned short(*)[72])(smem + 36864);    // Q[t][e]
  auto krow = (unsigned short(*)[72])(smem + 46080);    // K[s][e]
  auto vt   = (unsigned short(*)[72])(smem + 55296);    // V^T[o][t]
  auto As   = xs;
  auto SpT  = wqT;                                      // Sprev^T[o][e]

  const int tid = threadIdx.x;
  const int blk = blockIdx.x;
  const int c = blk & 63, bh = blk >> 6, h = bh & 15, b = bh >> 4;
  const int lane = tid & 63, w = tid >> 6;
  const int ll = lane & 15, hl = lane >> 4;

  // early global loads of prev state (overlap with staging/QKV)
  const float* stp = states + (size_t)blk * STSZ;
  float spreg[17];
#pragma unroll
  for (int j = 0; j < 17; ++j) {
    int i = tid + j * 256;
    spreg[j] = (i < STSZ) ? stp[i] : 0.f;
  }

  const float* xp = x + ((size_t)(b * Sv + c * 64)) * Dv + h * 64;
  for (int i = tid; i < 4096; i += 256) {
    int r = i >> 6, d = i & 63;
    xs[r][d]  = f2b(xp[(size_t)r * Dv + d]);
    wqT[d][r] = f2b(Wq[h * 4096 + i]);
    wkT[d][r] = f2b(Wk[h * 4096 + i]);
    wvT[d][r] = f2b(Wv[h * 4096 + i]);
  }
  __syncthreads();

  // ---- QKV projections ----
  const bf16x8 xa0 = *(const bf16x8*)&xs[w * 16 + ll][hl * 8];
  const bf16x8 xa1 = *(const bf16x8*)&xs[w * 16 + ll][32 + hl * 8];
  f32x4 acc[4];
  // Q -> qrow[t][e]
#pragma unroll
  for (int ct = 0; ct < 4; ++ct) {
    acc[ct] = zero4();
    bf16x8 b0 = *(const bf16x8*)&wqT[ct * 16 + ll][hl * 8];
    bf16x8 b1 = *(const bf16x8*)&wqT[ct * 16 + ll][32 + hl * 8];
    acc[ct] = MFMA(xa0, b0, acc[ct]);
    acc[ct] = MFMA(xa1, b1, acc[ct]);
  }
#pragma unroll
  for (int ct = 0; ct < 4; ++ct)
#pragma unroll
    for (int r = 0; r < 4; ++r)
      qrow[w * 16 + hl * 4 + r][ct * 16 + ll] = f2b(elu1(acc[ct][r]));
  // K -> krow[s][e]
#pragma unroll
  for (int ct = 0; ct < 4; ++ct) {
    acc[ct] = zero4();
    bf16x8 b0 = *(const bf16x8*)&wkT[ct * 16 + ll][hl * 8];
    bf16x8 b1 = *(const bf16x8*)&wkT[ct * 16 + ll][32 + hl * 8];
    acc[ct] = MFMA(xa0, b0, acc[ct]);
    acc[ct] = MFMA(xa1, b1, acc[ct]);
  }
#pragma unroll
  for (int ct = 0; ct < 4; ++ct)
#pragma unroll
    for (int r = 0; r < 4; ++r)
      krow[w * 16 + hl * 4 + r][ct * 16 + ll] = f2b(elu1(acc[ct][r]));
  // V -> vt[o][t]
#pragma unroll
  for (int ct = 0; ct < 4; ++ct) {
    acc[ct] = zero4();
    bf16x8 b0 = *(const bf16x8*)&wvT[ct * 16 + ll][hl * 8];
    bf16x8 b1 = *(const bf16x8*)&wvT[ct * 16 + ll][32 + hl * 8];
    acc[ct] = MFMA(xa0, b0, acc[ct]);
    acc[ct] = MFMA(xa1, b1, acc[ct]);
  }
#pragma unroll
  for (int ct = 0; ct < 4; ++ct)
#pragma unroll
    for (int r = 0; r < 4; ++r)
      vt[ct * 16 + ll][w * 16 + hl * 4 + r] = f2b(acc[ct][r]);
  __syncthreads();

  // ---- A = causal QK^T ----  (wave w owns rows [w*16, w*16+16))
  const bf16x8 qa0 = *(const bf16x8*)&qrow[w * 16 + ll][hl * 8];
  const bf16x8 qa1 = *(const bf16x8*)&qrow[w * 16 + ll][32 + hl * 8];
  f32x4 aacc[4];
#pragma unroll
  for (int ct = 0; ct < 4; ++ct) aacc[ct] = zero4();
  for (int ct = 0; ct <= w; ++ct) {
    bf16x8 b0 = *(const bf16x8*)&krow[ct * 16 + ll][hl * 8];
    bf16x8 b1 = *(const bf16x8*)&krow[ct * 16 + ll][32 + hl * 8];
    aacc[ct] = MFMA(qa0, b0, aacc[ct]);
    aacc[ct] = MFMA(qa1, b1, aacc[ct]);
  }
  { // causal mask on diagonal tile
    int ct = w;
#pragma unroll
    for (int r = 0; r < 4; ++r) {
      int t_ = w * 16 + hl * 4 + r, s_ = ct * 16 + ll;
      if (s_ > t_) aacc[ct][r] = 0.f;
    }
  }
  // fill SpT / zp (wqT, wkT regions now dead)
#pragma unroll
  for (int j = 0; j < 17; ++j) {
    int i = tid + j * 256;
    if (i < 4096) SpT[i & 63][i >> 6] = f2b(spreg[j]);
    else if (i < STSZ) zp[i - 4096] = spreg[j];
  }
  // rowsum(A) -> denA
  {
    float part[4];
#pragma unroll
    for (int r = 0; r < 4; ++r)
      part[r] = aacc[0][r] + aacc[1][r] + aacc[2][r] + aacc[3][r];
#pragma unroll
    for (int m = 1; m <= 8; m <<= 1)
#pragma unroll
      for (int r = 0; r < 4; ++r)
        part[r] += __shfl_xor(part[r], m);
    if (ll == 0)
#pragma unroll
      for (int r = 0; r < 4; ++r)
        denA[w * 16 + hl * 4 + r] = part[r];
  }
  // write As (bf16)
#pragma unroll
  for (int ct = 0; ct < 4; ++ct)
#pragma unroll
    for (int r = 0; r < 4; ++r)
      As[w * 16 + hl * 4 + r][ct * 16 + ll] = f2b(aacc[ct][r]);
  __syncthreads();

  // ---- num = A V + Q Sprev ; den0 = q . zprev ----
  f32x4 nacc[4];
#pragma unroll
  for (int ct = 0; ct < 4; ++ct) nacc[ct] = zero4();
  const int nks = (w < 2) ? 1 : 2;
  bf16x8 aa0 = *(const bf16x8*)&As[w * 16 + ll][hl * 8];
  bf16x8 aa1 = (nks > 1) ? *(const bf16x8*)&As[w * 16 + ll][32 + hl * 8] : aa0;
#pragma unroll
  for (int ct = 0; ct < 4; ++ct) {
    bf16x8 v0 = *(const bf16x8*)&vt[ct * 16 + ll][hl * 8];
    nacc[ct] = MFMA(aa0, v0, nacc[ct]);
    if (nks > 1) {
      bf16x8 v1 = *(const bf16x8*)&vt[ct * 16 + ll][32 + hl * 8];
      nacc[ct] = MFMA(aa1, v1, nacc[ct]);
    }
    bf16x8 s0 = *(const bf16x8*)&SpT[ct * 16 + ll][hl * 8];
    bf16x8 s1 = *(const bf16x8*)&SpT[ct * 16 + ll][32 + hl * 8];
    nacc[ct] = MFMA(qa0, s0, nacc[ct]);
    nacc[ct] = MFMA(qa1, s1, nacc[ct]);
  }
  {
    int t_ = tid & 63, p = tid >> 6;
    float s = 0.f;
#pragma unroll
    for (int j = 0; j < 16; ++j)
      s += b2f(qrow[t_][p * 16 + j]) * zp[p * 16 + j];
    den0p[p * 64 + t_] = s;
  }
  __syncthreads();

  // ---- y = num / den ----
  unsigned short* yp = y + ((size_t)(b * Sv + c * 64)) * (Hv * Ov) + h * 64;
#pragma unroll
  for (int r = 0; r < 4; ++r) {
    int t_ = w * 16 + hl * 4 + r;
    float den = denA[t_] + den0p[t_] + den0p[64 + t_] + den0p[128 + t_] +
                den0p[192 + t_] + 1e-6f;
    float inv = 1.f / den;
#pragma unroll
    for (int ct = 0; ct < 4; ++ct)
      yp[(size_t)t_ * (Hv * Ov) + ct * 16 + ll] = f2b(nacc[ct][r] * inv);
  }
}

// ---------------------------------------------------------------------------
// K4: out[row][o] = y[row][:] @ Wp ; 16 rows/block, MFMA over K=1024
// ---------------------------------------------------------------------------
__global__ __launch_bounds__(256) void k_proj(
    const unsigned short* __restrict__ y, const unsigned short* __restrict__ wpT,
    float* __restrict__ out)
{
  __shared__ __align__(16) unsigned short yt[16][136];
  __shared__ __align__(16) unsigned short wt[64][136];
  const int tid = threadIdx.x, lane = tid & 63, w = tid >> 6;
  const int ll = lane & 15, hl = lane >> 4;
  const size_t row0 = (size_t)blockIdx.x * 16;

  f32x4 acc = zero4();
  for (int kc = 0; kc < 8; ++kc) {
    __syncthreads();
    {
      int r = tid >> 4, c16 = tid & 15;
      *(uint4*)&yt[r][c16 * 8] =
          *(const uint4*)&y[(row0 + r) * 1024 + kc * 128 + c16 * 8];
    }
#pragma unroll
    for (int j = 0; j < 4; ++j) {
      int i = tid + j * 256, r = i >> 4, c16 = i & 15;
      *(uint4*)&wt[r][c16 * 8] =
          *(const uint4*)&wpT[(size_t)r * 1024 + kc * 128 + c16 * 8];
    }
    __syncthreads();
#pragma unroll
    for (int ks = 0; ks < 4; ++ks) {
      bf16x8 a = *(const bf16x8*)&yt[ll][ks * 32 + hl * 8];
      bf16x8 bb = *(const bf16x8*)&wt[w * 16 + ll][ks * 32 + hl * 8];
      acc = MFMA(a, bb, acc);
    }
  }
#pragma unroll
  for (int r = 0; r < 4; ++r)
    out[(row0 + hl * 4 + r) * 64 + w * 16 + ll] = acc[r];
}

// ---------------------------------------------------------------------------
extern "C" void kernel_launch(void* const* d_in, const int* in_sizes, int n_in,
                              void* d_out, int out_size, void* d_ws, size_t ws_size,
                              hipStream_t stream)
{
  const float* x  = (const float*)d_in[0];
  const float* Wq = (const float*)d_in[1];
  const float* Wk = (const float*)d_in[2];
  const float* Wv = (const float*)d_in[3];
  const float* Wp = (const float*)d_in[4];
  float* out = (float*)d_out;

  // ws: states f32 [4096*4160] (68.2MB) | y bf16 [16384*1024] (33.5MB) | wpT bf16 [65536]
  float* states = (float*)d_ws;
  unsigned short* y = (unsigned short*)(states + (size_t)BHv * NCv * STSZ);
  unsigned short* wpT = y + (size_t)16384 * 1024;

  hipLaunchKernelGGL(k_prep, dim3(64), dim3(256), 0, stream, Wp, wpT);
  hipLaunchKernelGGL(k_chunk_state, dim3(BHv * NCv), dim3(256), 0, stream,
                     x, Wk, Wv, states);
  hipLaunchKernelGGL(k_prefix, dim3(BHv), dim3(1024), 0, stream, states);
  hipLaunchKernelGGL(k_chunk_out, dim3(BHv * NCv), dim3(256), 0, stream,
                     x, Wq, Wk, Wv, states, y);
  hipLaunchKernelGGL(k_proj, dim3((Bv * Sv) / 16), dim3(256), 0, stream,
                     y, wpT, out);
}

// Round 3
// 168.603 us; speedup vs baseline: 8.5160x; 1.2008x over previous
//
#include <hip/hip_runtime.h>
#include <hip/hip_bf16.h>

// Problem constants
#define Bv 4
#define Sv 4096
#define Dv 1024
#define Hv 16
#define Ov 64
#define NCv 64
#define BHv 64

typedef __attribute__((ext_vector_type(8))) short bf16x8;
typedef __attribute__((ext_vector_type(4))) unsigned short u16x4;
typedef __attribute__((ext_vector_type(8))) unsigned short u16x8;
typedef __attribute__((ext_vector_type(4))) float f32x4;
#define MFMA(a, b, c) __builtin_amdgcn_mfma_f32_16x16x32_bf16(a, b, c, 0, 0, 0)

__device__ __forceinline__ unsigned short f2bs(float f) {
  union { __hip_bfloat16 h; unsigned short u; } v;
  v.h = __float2bfloat16(f);
  return v.u;
}
__device__ __forceinline__ float b2f(unsigned short u) {
  union { unsigned u; float f; } v; v.u = ((unsigned)u) << 16; return v.f;
}
__device__ __forceinline__ float elu1(float a) {
  return a > 0.f ? a + 1.f : expf(a);
}
__device__ __forceinline__ f32x4 zero4() {
  f32x4 v = {0.f, 0.f, 0.f, 0.f}; return v;
}

// ---------------------------------------------------------------------------
// K0 prep: x f32 -> xb bf16 (same layout); Wq/Wk/Wv [h][d][o] -> bf16 [h][o][d];
//          Wp [d][o2] -> bf16 [o2][d]
// blocks: 0..8191 x | 8192..8207 per-head weights | 8208..8271 wpT
// ---------------------------------------------------------------------------
__global__ __launch_bounds__(256) void k_prep(
    const float* __restrict__ x, const float* __restrict__ Wq,
    const float* __restrict__ Wk, const float* __restrict__ Wv,
    const float* __restrict__ Wp, unsigned short* __restrict__ xb,
    unsigned short* __restrict__ wqT, unsigned short* __restrict__ wkT,
    unsigned short* __restrict__ wvT, unsigned short* __restrict__ wpT)
{
  const int blk = blockIdx.x, tid = threadIdx.x;
  if (blk < 8192) {
    size_t base = (size_t)blk * 2048 + (size_t)tid * 8;
    float4 f0 = *(const float4*)(x + base);
    float4 f1 = *(const float4*)(x + base + 4);
    u16x8 o;
    o[0] = f2bs(f0.x); o[1] = f2bs(f0.y); o[2] = f2bs(f0.z); o[3] = f2bs(f0.w);
    o[4] = f2bs(f1.x); o[5] = f2bs(f1.y); o[6] = f2bs(f1.z); o[7] = f2bs(f1.w);
    *(u16x8*)(xb + base) = o;
  } else if (blk < 8208) {
    int h = blk - 8192;
    for (int j = tid; j < 4096; j += 256) {       // j = o*64 + d (output idx)
      int o = j >> 6, d = j & 63;
      int src = h * 4096 + d * 64 + o;
      wqT[h * 4096 + j] = f2bs(Wq[src]);
      wkT[h * 4096 + j] = f2bs(Wk[src]);
      wvT[h * 4096 + j] = f2bs(Wv[src]);
    }
  } else {
    int b2 = blk - 8208;
#pragma unroll
    for (int k = 0; k < 4; ++k) {
      int j = b2 * 1024 + tid + k * 256;          // j = o*1024 + d (output idx)
      int o = j >> 10, d = j & 1023;
      wpT[j] = f2bs(Wp[d * 64 + o]);
    }
  }
}

// ---------------------------------------------------------------------------
// K1: per (bh,chunk): K=elu1(x Wk), V=x Wv;
//     mir[blk][o*64+e] = bf16(sum_t K[t][e] V[t][o]); zmir[blk][e] = colsum K
// ---------------------------------------------------------------------------
__global__ __launch_bounds__(256) void k_chunk_state(
    const unsigned short* __restrict__ xb, const unsigned short* __restrict__ wkT,
    const unsigned short* __restrict__ wvT, unsigned short* __restrict__ mir,
    float* __restrict__ zmir)
{
  __shared__ __align__(16) unsigned short kT[64][72];   // kT[e][t]
  __shared__ __align__(16) unsigned short vT[64][72];   // vT[o][t]
  __shared__ float zpart[4][64];

  const int tid = threadIdx.x, blk = blockIdx.x;
  const int c = blk & 63, bh = blk >> 6, h = bh & 15, b = bh >> 4;
  const int lane = tid & 63, w = tid >> 6;
  const int ll = lane & 15, hl = lane >> 4;

  const size_t xrow = ((size_t)(b * Sv + c * 64 + w * 16 + ll)) * 1024 + h * 64;
  const bf16x8 xa0 = *(const bf16x8*)(xb + xrow + hl * 8);
  const bf16x8 xa1 = *(const bf16x8*)(xb + xrow + 32 + hl * 8);

  // K = elu1(x Wk) -> kT[e][t] (b64 packed writes) + zpart
  const unsigned short* wk = wkT + h * 4096;
#pragma unroll
  for (int ct = 0; ct < 4; ++ct) {
    bf16x8 b0 = *(const bf16x8*)(wk + (ct * 16 + ll) * 64 + hl * 8);
    bf16x8 b1 = *(const bf16x8*)(wk + (ct * 16 + ll) * 64 + 32 + hl * 8);
    f32x4 a = zero4(); a = MFMA(xa0, b0, a); a = MFMA(xa1, b1, a);
    u16x4 p; float part = 0.f;
#pragma unroll
    for (int r = 0; r < 4; ++r) { float kv = elu1(a[r]); part += kv; p[r] = f2bs(kv); }
    *(u16x4*)&kT[ct * 16 + ll][w * 16 + hl * 4] = p;
    part += __shfl_xor(part, 16);
    part += __shfl_xor(part, 32);
    if (hl == 0) zpart[w][ct * 16 + ll] = part;
  }
  // V = x Wv -> vT[o][t]
  const unsigned short* wv = wvT + h * 4096;
#pragma unroll
  for (int ct = 0; ct < 4; ++ct) {
    bf16x8 b0 = *(const bf16x8*)(wv + (ct * 16 + ll) * 64 + hl * 8);
    bf16x8 b1 = *(const bf16x8*)(wv + (ct * 16 + ll) * 64 + 32 + hl * 8);
    f32x4 a = zero4(); a = MFMA(xa0, b0, a); a = MFMA(xa1, b1, a);
    u16x4 p;
#pragma unroll
    for (int r = 0; r < 4; ++r) p[r] = f2bs(a[r]);
    *(u16x4*)&vT[ct * 16 + ll][w * 16 + hl * 4] = p;
  }
  __syncthreads();

  // KtV: A = kT[e][t], B = vT[o][t]; write transposed [o][e] bf16 to mir
  const bf16x8 ka0 = *(const bf16x8*)&kT[w * 16 + ll][hl * 8];
  const bf16x8 ka1 = *(const bf16x8*)&kT[w * 16 + ll][32 + hl * 8];
  unsigned short* mp = mir + (size_t)blk * 4096;
#pragma unroll
  for (int ct = 0; ct < 4; ++ct) {
    bf16x8 v0 = *(const bf16x8*)&vT[ct * 16 + ll][hl * 8];
    bf16x8 v1 = *(const bf16x8*)&vT[ct * 16 + ll][32 + hl * 8];
    f32x4 s = zero4(); s = MFMA(ka0, v0, s); s = MFMA(ka1, v1, s);
    u16x4 p;
#pragma unroll
    for (int r = 0; r < 4; ++r) p[r] = f2bs(s[r]);
    *(u16x4*)&mp[(ct * 16 + ll) * 64 + w * 16 + hl * 4] = p;
  }
  if (tid < 64)
    zmir[(size_t)blk * 64 + tid] =
        zpart[0][tid] + zpart[1][tid] + zpart[2][tid] + zpart[3][tid];
}

// ---------------------------------------------------------------------------
// K2: in-place exclusive prefix over chunks (fp32 carry, bf16 storage)
// grid = 64 bh * 17 groups
// ---------------------------------------------------------------------------
__global__ __launch_bounds__(256) void k_prefix(
    unsigned short* __restrict__ mir, float* __restrict__ zmir)
{
  const int bh = blockIdx.x / 17, g = blockIdx.x % 17;
  const int tid = threadIdx.x;
  if (g < 16) {
    size_t base = (size_t)bh * 64 * 4096 + g * 256 + tid;
    float carry = 0.f;
    for (int cc = 0; cc < 64; ++cc) {
      size_t idx = base + (size_t)cc * 4096;
      float v = b2f(mir[idx]);
      mir[idx] = f2bs(carry);
      carry += v;
    }
  } else if (tid < 64) {
    size_t base = (size_t)bh * 64 * 64 + tid;
    float carry = 0.f;
    for (int cc = 0; cc < 64; ++cc) {
      size_t idx = base + (size_t)cc * 64;
      float v = zmir[idx];
      zmir[idx] = carry;
      carry += v;
    }
  }
}

// ---------------------------------------------------------------------------
// K3: per (bh,chunk): y = (Q Sprev + tril(Q K^T) V) / (q.zprev + rowsum + eps)
// ---------------------------------------------------------------------------
__global__ __launch_bounds__(256) void k_chunk_out(
    const unsigned short* __restrict__ xb, const unsigned short* __restrict__ wqT,
    const unsigned short* __restrict__ wkT, const unsigned short* __restrict__ wvT,
    const unsigned short* __restrict__ mir, const float* __restrict__ zmir,
    unsigned short* __restrict__ y)
{
  __shared__ __align__(16) unsigned short qrow[64][72];  // Q[t][e]
  __shared__ __align__(16) unsigned short krow[64][72];  // K[s][e]
  __shared__ __align__(16) unsigned short vT[64][72];    // V^T[o][s]
  __shared__ __align__(16) unsigned short As[64][72];    // A[t][s]

  const int tid = threadIdx.x, blk = blockIdx.x;
  const int c = blk & 63, bh = blk >> 6, h = bh & 15, b = bh >> 4;
  const int lane = tid & 63, w = tid >> 6;
  const int ll = lane & 15, hl = lane >> 4;

  const size_t xrow = ((size_t)(b * Sv + c * 64 + w * 16 + ll)) * 1024 + h * 64;
  const bf16x8 xa0 = *(const bf16x8*)(xb + xrow + hl * 8);
  const bf16x8 xa1 = *(const bf16x8*)(xb + xrow + 32 + hl * 8);

  // --- Q (+ den0 = q . zprev, register-resident) ---
  float den0[4] = {0.f, 0.f, 0.f, 0.f};
  {
    const unsigned short* wq = wqT + h * 4096;
    const float* zp = zmir + (size_t)blk * 64;
    f32x4 qacc[4];
#pragma unroll
    for (int ct = 0; ct < 4; ++ct) {
      bf16x8 b0 = *(const bf16x8*)(wq + (ct * 16 + ll) * 64 + hl * 8);
      bf16x8 b1 = *(const bf16x8*)(wq + (ct * 16 + ll) * 64 + 32 + hl * 8);
      f32x4 a = zero4(); a = MFMA(xa0, b0, a); a = MFMA(xa1, b1, a);
      qacc[ct] = a;
    }
#pragma unroll
    for (int ct = 0; ct < 4; ++ct) {
      float zv = zp[ct * 16 + ll];
#pragma unroll
      for (int r = 0; r < 4; ++r) {
        float q = elu1(qacc[ct][r]);
        den0[r] += q * zv;
        qrow[w * 16 + hl * 4 + r][ct * 16 + ll] = f2bs(q);
      }
    }
#pragma unroll
    for (int m = 1; m <= 8; m <<= 1)
#pragma unroll
      for (int r = 0; r < 4; ++r) den0[r] += __shfl_xor(den0[r], m);
  }
  // --- K ---
  {
    const unsigned short* wk = wkT + h * 4096;
#pragma unroll
    for (int ct = 0; ct < 4; ++ct) {
      bf16x8 b0 = *(const bf16x8*)(wk + (ct * 16 + ll) * 64 + hl * 8);
      bf16x8 b1 = *(const bf16x8*)(wk + (ct * 16 + ll) * 64 + 32 + hl * 8);
      f32x4 a = zero4(); a = MFMA(xa0, b0, a); a = MFMA(xa1, b1, a);
#pragma unroll
      for (int r = 0; r < 4; ++r)
        krow[w * 16 + hl * 4 + r][ct * 16 + ll] = f2bs(elu1(a[r]));
    }
  }
  // --- V -> vT[o][t] (b64 packed) ---
  {
    const unsigned short* wv = wvT + h * 4096;
#pragma unroll
    for (int ct = 0; ct < 4; ++ct) {
      bf16x8 b0 = *(const bf16x8*)(wv + (ct * 16 + ll) * 64 + hl * 8);
      bf16x8 b1 = *(const bf16x8*)(wv + (ct * 16 + ll) * 64 + 32 + hl * 8);
      f32x4 a = zero4(); a = MFMA(xa0, b0, a); a = MFMA(xa1, b1, a);
      u16x4 p;
#pragma unroll
      for (int r = 0; r < 4; ++r) p[r] = f2bs(a[r]);
      *(u16x4*)&vT[ct * 16 + ll][w * 16 + hl * 4] = p;
    }
  }
  __syncthreads();   // the only block-wide barrier

  // --- A = tril(Q K^T); rowsum in regs; num = Q.Sprev (MFMA) ---
  const bf16x8 qa0 = *(const bf16x8*)&qrow[w * 16 + ll][hl * 8];
  const bf16x8 qa1 = *(const bf16x8*)&qrow[w * 16 + ll][32 + hl * 8];
  f32x4 nacc[4];
  float inv[4];
  {
    f32x4 aacc[4];
#pragma unroll
    for (int ct = 0; ct < 4; ++ct) {
      if (ct <= w) {   // wave-uniform branch
        bf16x8 b0 = *(const bf16x8*)&krow[ct * 16 + ll][hl * 8];
        bf16x8 b1 = *(const bf16x8*)&krow[ct * 16 + ll][32 + hl * 8];
        f32x4 a = zero4(); a = MFMA(qa0, b0, a); a = MFMA(qa1, b1, a);
        aacc[ct] = a;
      } else {
        aacc[ct] = zero4();
      }
    }
    // causal mask on the diagonal tile (ct == w)
#pragma unroll
    for (int r = 0; r < 4; ++r)
      if (ll > hl * 4 + r) aacc[w][r] = 0.f;
    // rowsum(A) -> denA (per-lane, reduced over ll)
    float denA[4];
#pragma unroll
    for (int r = 0; r < 4; ++r)
      denA[r] = aacc[0][r] + aacc[1][r] + aacc[2][r] + aacc[3][r];
#pragma unroll
    for (int m = 1; m <= 8; m <<= 1)
#pragma unroll
      for (int r = 0; r < 4; ++r) denA[r] += __shfl_xor(denA[r], m);
    // store As (bf16; ct>w tiles are zeros)
#pragma unroll
    for (int ct = 0; ct < 4; ++ct)
#pragma unroll
      for (int r = 0; r < 4; ++r)
        As[w * 16 + hl * 4 + r][ct * 16 + ll] = f2bs(aacc[ct][r]);
    // num = Q . Sprev  (Sprev fragments straight from global bf16 mirror)
    const unsigned short* sp = mir + (size_t)blk * 4096;
#pragma unroll
    for (int ct = 0; ct < 4; ++ct) {
      bf16x8 s0 = *(const bf16x8*)(sp + (ct * 16 + ll) * 64 + hl * 8);
      bf16x8 s1 = *(const bf16x8*)(sp + (ct * 16 + ll) * 64 + 32 + hl * 8);
      f32x4 a = zero4(); a = MFMA(qa0, s0, a); a = MFMA(qa1, s1, a);
      nacc[ct] = a;
    }
#pragma unroll
    for (int r = 0; r < 4; ++r)
      inv[r] = 1.f / (denA[r] + den0[r] + 1e-6f);
  }
  // --- num += A V (own-wave rows; in-wave LDS dependency, no barrier) ---
  {
    const bf16x8 aa0 = *(const bf16x8*)&As[w * 16 + ll][hl * 8];
    const bf16x8 aa1 = *(const bf16x8*)&As[w * 16 + ll][32 + hl * 8];
#pragma unroll
    for (int ct = 0; ct < 4; ++ct) {
      bf16x8 v0 = *(const bf16x8*)&vT[ct * 16 + ll][hl * 8];
      bf16x8 v1 = *(const bf16x8*)&vT[ct * 16 + ll][32 + hl * 8];
      nacc[ct] = MFMA(aa0, v0, nacc[ct]);
      nacc[ct] = MFMA(aa1, v1, nacc[ct]);
    }
  }
  // --- y = num * inv ---
  unsigned short* yp = y + ((size_t)(b * Sv + c * 64)) * 1024 + h * 64;
#pragma unroll
  for (int ct = 0; ct < 4; ++ct)
#pragma unroll
    for (int r = 0; r < 4; ++r)
      yp[(size_t)(w * 16 + hl * 4 + r) * 1024 + ct * 16 + ll] =
          f2bs(nacc[ct][r] * inv[r]);
}

// ---------------------------------------------------------------------------
// K4: out = y @ Wp. 64 rows/block, 4 waves, LDS-free, barrier-free.
// ---------------------------------------------------------------------------
__global__ __launch_bounds__(256) void k_proj(
    const unsigned short* __restrict__ y, const unsigned short* __restrict__ wpT,
    float* __restrict__ out)
{
  const int tid = threadIdx.x, lane = tid & 63, w = tid >> 6;
  const int ll = lane & 15, hl = lane >> 4;
  const size_t row0 = (size_t)blockIdx.x * 64 + w * 16;

  f32x4 acc[4] = {zero4(), zero4(), zero4(), zero4()};
  const unsigned short* yrow = y + (row0 + ll) * 1024;
  for (int kc = 0; kc < 32; ++kc) {
    bf16x8 a = *(const bf16x8*)(yrow + kc * 32 + hl * 8);
#pragma unroll
    for (int ct = 0; ct < 4; ++ct) {
      bf16x8 bb = *(const bf16x8*)(wpT + (size_t)(ct * 16 + ll) * 1024 + kc * 32 + hl * 8);
      acc[ct] = MFMA(a, bb, acc[ct]);
    }
  }
#pragma unroll
  for (int ct = 0; ct < 4; ++ct)
#pragma unroll
    for (int r = 0; r < 4; ++r)
      out[(row0 + hl * 4 + r) * 64 + ct * 16 + ll] = acc[ct][r];
}

// ---------------------------------------------------------------------------
extern "C" void kernel_launch(void* const* d_in, const int* in_sizes, int n_in,
                              void* d_out, int out_size, void* d_ws, size_t ws_size,
                              hipStream_t stream)
{
  const float* x  = (const float*)d_in[0];
  const float* Wq = (const float*)d_in[1];
  const float* Wk = (const float*)d_in[2];
  const float* Wv = (const float*)d_in[3];
  const float* Wp = (const float*)d_in[4];
  float* out = (float*)d_out;

  // ws layout (bytes):
  //   mir  bf16 [4096][4096]  33.55 MB   (chunk KtV^T sums -> exclusive prefix)
  //   zmir f32  [4096][64]     1.05 MB
  //   xb   bf16 [16.7M]       33.55 MB
  //   wqT/wkT/wvT bf16 [16][64][64], wpT bf16 [64][1024]
  //   y    bf16 [16384][1024] 33.55 MB
  unsigned short* mir = (unsigned short*)d_ws;
  float* zmir = (float*)((char*)d_ws + 33554432);
  unsigned short* xb  = (unsigned short*)((char*)d_ws + 34603008);
  unsigned short* wqT = xb + 16777216;
  unsigned short* wkT = wqT + 65536;
  unsigned short* wvT = wkT + 65536;
  unsigned short* wpT = wvT + 65536;
  unsigned short* yb  = wpT + 65536;

  hipLaunchKernelGGL(k_prep, dim3(8272), dim3(256), 0, stream,
                     x, Wq, Wk, Wv, Wp, xb, wqT, wkT, wvT, wpT);
  hipLaunchKernelGGL(k_chunk_state, dim3(BHv * NCv), dim3(256), 0, stream,
                     xb, wkT, wvT, mir, zmir);
  hipLaunchKernelGGL(k_prefix, dim3(BHv * 17), dim3(256), 0, stream, mir, zmir);
  hipLaunchKernelGGL(k_chunk_out, dim3(BHv * NCv), dim3(256), 0, stream,
                     xb, wqT, wkT, wvT, mir, zmir, yb);
  hipLaunchKernelGGL(k_proj, dim3(256), dim3(256), 0, stream, yb, wpT, out);
}

// Round 4
// 158.435 us; speedup vs baseline: 9.0625x; 1.0642x over previous
//
#include <hip/hip_runtime.h>
#include <hip/hip_bf16.h>

// Problem constants
#define Bv 4
#define Sv 4096
#define Dv 1024
#define Hv 16
#define Ov 64
#define NCv 64
#define BHv 64

typedef __attribute__((ext_vector_type(8))) short bf16x8;
typedef __attribute__((ext_vector_type(4))) unsigned short u16x4;
typedef __attribute__((ext_vector_type(8))) unsigned short u16x8;
typedef __attribute__((ext_vector_type(4))) float f32x4;
#define MFMA(a, b, c) __builtin_amdgcn_mfma_f32_16x16x32_bf16(a, b, c, 0, 0, 0)

__device__ __forceinline__ unsigned short f2bs(float f) {
  union { __hip_bfloat16 h; unsigned short u; } v;
  v.h = __float2bfloat16(f);
  return v.u;
}
__device__ __forceinline__ float b2f(unsigned short u) {
  union { unsigned u; float f; } v; v.u = ((unsigned)u) << 16; return v.f;
}
__device__ __forceinline__ float elu1(float a) {
  return a > 0.f ? a + 1.f : expf(a);
}
__device__ __forceinline__ f32x4 zero4() {
  f32x4 v = {0.f, 0.f, 0.f, 0.f}; return v;
}
__device__ __forceinline__ bf16x8 pack8(float4 a, float4 b) {
  union { u16x8 u; bf16x8 h; } r;
  r.u[0] = f2bs(a.x); r.u[1] = f2bs(a.y); r.u[2] = f2bs(a.z); r.u[3] = f2bs(a.w);
  r.u[4] = f2bs(b.x); r.u[5] = f2bs(b.y); r.u[6] = f2bs(b.z); r.u[7] = f2bs(b.w);
  return r.h;
}

// ---------------------------------------------------------------------------
// K0 prep: Wq/Wk/Wv [h][d][o] -> bf16 [h][o][d]; Wp [d][o2] -> bf16 [o2][d]
// blocks 0..15: per-head qkv; 16..79: wpT
// ---------------------------------------------------------------------------
__global__ __launch_bounds__(256) void k_prep_w(
    const float* __restrict__ Wq, const float* __restrict__ Wk,
    const float* __restrict__ Wv, const float* __restrict__ Wp,
    unsigned short* __restrict__ wqT, unsigned short* __restrict__ wkT,
    unsigned short* __restrict__ wvT, unsigned short* __restrict__ wpT)
{
  const int blk = blockIdx.x, tid = threadIdx.x;
  if (blk < 16) {
    int h = blk;
    for (int j = tid; j < 4096; j += 256) {       // j = o*64 + d (output idx)
      int o = j >> 6, d = j & 63;
      int src = h * 4096 + d * 64 + o;
      wqT[h * 4096 + j] = f2bs(Wq[src]);
      wkT[h * 4096 + j] = f2bs(Wk[src]);
      wvT[h * 4096 + j] = f2bs(Wv[src]);
    }
  } else {
    int b2 = blk - 16;
#pragma unroll
    for (int k = 0; k < 4; ++k) {
      int j = b2 * 1024 + tid + k * 256;          // j = o2*1024 + d
      int o = j >> 10, d = j & 1023;
      wpT[j] = f2bs(Wp[d * 64 + o]);
    }
  }
}

// ---------------------------------------------------------------------------
// K1: per (bh,chunk): K=elu1(x Wk), V=x Wv
//   publishes: krow_g [s][e] bf16, vtg [o][t] bf16,
//              mir [o][e] = (K^T V)^T bf16, zmir [e] f32
// ---------------------------------------------------------------------------
__global__ __launch_bounds__(256) void k_chunk_state(
    const float* __restrict__ x, const unsigned short* __restrict__ wkT,
    const unsigned short* __restrict__ wvT, unsigned short* __restrict__ mir,
    float* __restrict__ zmir, unsigned short* __restrict__ krow_g,
    unsigned short* __restrict__ vtg)
{
  __shared__ __align__(16) unsigned short kT[64][72];     // K^T[e][t]
  __shared__ __align__(16) unsigned short krow_s[64][72]; // K[s][e]
  __shared__ __align__(16) unsigned short vT[64][72];     // V^T[o][t]
  __shared__ float zpart[4][64];

  const int tid = threadIdx.x, blk = blockIdx.x;
  const int c = blk & 63, bh = blk >> 6, h = bh & 15, b = bh >> 4;
  const int lane = tid & 63, w = tid >> 6;
  const int ll = lane & 15, hl = lane >> 4;

  // x fragment (f32 -> bf16 in-register)
  const float* xr = x + ((size_t)(b * Sv + c * 64 + w * 16 + ll)) * 1024 + h * 64;
  float4 f0 = *(const float4*)(xr + hl * 8);
  float4 f1 = *(const float4*)(xr + hl * 8 + 4);
  float4 f2 = *(const float4*)(xr + 32 + hl * 8);
  float4 f3 = *(const float4*)(xr + 32 + hl * 8 + 4);
  const bf16x8 xa0 = pack8(f0, f1);
  const bf16x8 xa1 = pack8(f2, f3);

  // K = elu1(x Wk) -> kT + krow_s + zpart
  const unsigned short* wk = wkT + h * 4096;
#pragma unroll
  for (int ct = 0; ct < 4; ++ct) {
    bf16x8 b0 = *(const bf16x8*)(wk + (ct * 16 + ll) * 64 + hl * 8);
    bf16x8 b1 = *(const bf16x8*)(wk + (ct * 16 + ll) * 64 + 32 + hl * 8);
    f32x4 a = zero4(); a = MFMA(xa0, b0, a); a = MFMA(xa1, b1, a);
    u16x4 p; float part = 0.f;
#pragma unroll
    for (int r = 0; r < 4; ++r) {
      float kv = elu1(a[r]); part += kv;
      unsigned short kb = f2bs(kv);
      p[r] = kb;
      krow_s[w * 16 + hl * 4 + r][ct * 16 + ll] = kb;
    }
    *(u16x4*)&kT[ct * 16 + ll][w * 16 + hl * 4] = p;
    part += __shfl_xor(part, 16);
    part += __shfl_xor(part, 32);
    if (hl == 0) zpart[w][ct * 16 + ll] = part;
  }
  // V = x Wv -> vT[o][t]
  const unsigned short* wv = wvT + h * 4096;
#pragma unroll
  for (int ct = 0; ct < 4; ++ct) {
    bf16x8 b0 = *(const bf16x8*)(wv + (ct * 16 + ll) * 64 + hl * 8);
    bf16x8 b1 = *(const bf16x8*)(wv + (ct * 16 + ll) * 64 + 32 + hl * 8);
    f32x4 a = zero4(); a = MFMA(xa0, b0, a); a = MFMA(xa1, b1, a);
    u16x4 p;
#pragma unroll
    for (int r = 0; r < 4; ++r) p[r] = f2bs(a[r]);
    *(u16x4*)&vT[ct * 16 + ll][w * 16 + hl * 4] = p;
  }
  __syncthreads();

  // KtV: C[e][o]; write transposed [o][e] to mir
  const bf16x8 ka0 = *(const bf16x8*)&kT[w * 16 + ll][hl * 8];
  const bf16x8 ka1 = *(const bf16x8*)&kT[w * 16 + ll][32 + hl * 8];
  unsigned short* mp = mir + (size_t)blk * 4096;
#pragma unroll
  for (int ct = 0; ct < 4; ++ct) {
    bf16x8 v0 = *(const bf16x8*)&vT[ct * 16 + ll][hl * 8];
    bf16x8 v1 = *(const bf16x8*)&vT[ct * 16 + ll][32 + hl * 8];
    f32x4 s = zero4(); s = MFMA(ka0, v0, s); s = MFMA(ka1, v1, s);
    u16x4 p;
#pragma unroll
    for (int r = 0; r < 4; ++r) p[r] = f2bs(s[r]);
    *(u16x4*)&mp[(ct * 16 + ll) * 64 + w * 16 + hl * 4] = p;
  }
  // coalesced publish of krow / vT
  unsigned short* kg = krow_g + (size_t)blk * 4096;
  unsigned short* vg = vtg + (size_t)blk * 4096;
#pragma unroll
  for (int it = 0; it < 2; ++it) {
    int j = tid * 8 + it * 2048;
    int r = j >> 6, col = j & 63;
    *(uint4*)&kg[j] = *(const uint4*)&krow_s[r][col];
    *(uint4*)&vg[j] = *(const uint4*)&vT[r][col];
  }
  if (tid < 64)
    zmir[(size_t)blk * 64 + tid] =
        zpart[0][tid] + zpart[1][tid] + zpart[2][tid] + zpart[3][tid];
}

// ---------------------------------------------------------------------------
// K2: in-place exclusive prefix over chunks (fp32 carry, bf16 storage)
// grid = 64 bh * 17 groups
// ---------------------------------------------------------------------------
__global__ __launch_bounds__(256) void k_prefix(
    unsigned short* __restrict__ mir, float* __restrict__ zmir)
{
  const int bh = blockIdx.x / 17, g = blockIdx.x % 17;
  const int tid = threadIdx.x;
  if (g < 16) {
    size_t base = (size_t)bh * 64 * 4096 + g * 256 + tid;
    float carry = 0.f;
    for (int cc = 0; cc < 64; ++cc) {
      size_t idx = base + (size_t)cc * 4096;
      float v = b2f(mir[idx]);
      mir[idx] = f2bs(carry);
      carry += v;
    }
  } else if (tid < 64) {
    size_t base = (size_t)bh * 64 * 64 + tid;
    float carry = 0.f;
    for (int cc = 0; cc < 64; ++cc) {
      size_t idx = base + (size_t)cc * 64;
      float v = zmir[idx];
      zmir[idx] = carry;
      carry += v;
    }
  }
}

// ---------------------------------------------------------------------------
// K3: per (b,chunk,head-quarter): for 4 heads:
//   Q = elu1(x Wq);  A = tril(Q K^T);  y_h = (Q Sprev + A V) / den
//   oacc += y_h @ Wp[h*64:(h+1)*64, :]
// Barrier-free: all cross-row operands come from global; transposes in-wave.
// ---------------------------------------------------------------------------
__global__ __launch_bounds__(256) void k_out(
    const float* __restrict__ x, const unsigned short* __restrict__ wqT,
    const unsigned short* __restrict__ krow_g, const unsigned short* __restrict__ vtg,
    const unsigned short* __restrict__ mir, const float* __restrict__ zmir,
    const unsigned short* __restrict__ wpT, float* __restrict__ partial)
{
  __shared__ __align__(16) unsigned short qs[64][72];
  __shared__ __align__(16) unsigned short As[64][72];
  __shared__ __align__(16) unsigned short ys[64][72];

  const int tid = threadIdx.x, bid = blockIdx.x;
  const int g = bid & 3, c = (bid >> 2) & 63, b = bid >> 8;
  const int lane = tid & 63, w = tid >> 6;
  const int ll = lane & 15, hl = lane >> 4;

  f32x4 oacc[4] = {zero4(), zero4(), zero4(), zero4()};

#pragma unroll 1
  for (int hi = 0; hi < 4; ++hi) {
    const int h = g * 4 + hi;
    const size_t sblk = (size_t)((b * 16 + h) * 64 + c);

    // x fragment
    const float* xr = x + ((size_t)(b * Sv + c * 64 + w * 16 + ll)) * 1024 + h * 64;
    float4 f0 = *(const float4*)(xr + hl * 8);
    float4 f1 = *(const float4*)(xr + hl * 8 + 4);
    float4 f2 = *(const float4*)(xr + 32 + hl * 8);
    float4 f3 = *(const float4*)(xr + 32 + hl * 8 + 4);
    const bf16x8 xa0 = pack8(f0, f1);
    const bf16x8 xa1 = pack8(f2, f3);

    // Q projection
    const unsigned short* wq = wqT + h * 4096;
    f32x4 qacc[4];
#pragma unroll
    for (int ct = 0; ct < 4; ++ct) {
      bf16x8 b0 = *(const bf16x8*)(wq + (ct * 16 + ll) * 64 + hl * 8);
      bf16x8 b1 = *(const bf16x8*)(wq + (ct * 16 + ll) * 64 + 32 + hl * 8);
      f32x4 a = zero4(); a = MFMA(xa0, b0, a); a = MFMA(xa1, b1, a);
      qacc[ct] = a;
    }
    // elu + den0 = q . zprev + qs transpose
    const float* zp = zmir + sblk * 64;
    float den0[4] = {0.f, 0.f, 0.f, 0.f};
#pragma unroll
    for (int ct = 0; ct < 4; ++ct) {
      float zv = zp[ct * 16 + ll];
#pragma unroll
      for (int r = 0; r < 4; ++r) {
        float q = elu1(qacc[ct][r]);
        den0[r] += q * zv;
        qs[w * 16 + hl * 4 + r][ct * 16 + ll] = f2bs(q);
      }
    }
#pragma unroll
    for (int m = 1; m <= 8; m <<= 1)
#pragma unroll
      for (int r = 0; r < 4; ++r) den0[r] += __shfl_xor(den0[r], m);

    const bf16x8 qa0 = *(const bf16x8*)&qs[w * 16 + ll][hl * 8];
    const bf16x8 qa1 = *(const bf16x8*)&qs[w * 16 + ll][32 + hl * 8];

    // A = tril(Q K^T)  (K fragments from global)
    const unsigned short* kg = krow_g + sblk * 4096;
    f32x4 aacc[4];
#pragma unroll
    for (int ct = 0; ct < 4; ++ct) {
      if (ct <= w) {   // wave-uniform
        bf16x8 b0 = *(const bf16x8*)(kg + (ct * 16 + ll) * 64 + hl * 8);
        bf16x8 b1 = *(const bf16x8*)(kg + (ct * 16 + ll) * 64 + 32 + hl * 8);
        f32x4 a = zero4(); a = MFMA(qa0, b0, a); a = MFMA(qa1, b1, a);
        if (ct == w) {  // causal mask on diagonal tile (static index!)
#pragma unroll
          for (int r = 0; r < 4; ++r)
            if (ll > hl * 4 + r) a[r] = 0.f;
        }
        aacc[ct] = a;
      } else {
        aacc[ct] = zero4();
      }
    }
    // rowsum(A)
    float denA[4];
#pragma unroll
    for (int r = 0; r < 4; ++r)
      denA[r] = aacc[0][r] + aacc[1][r] + aacc[2][r] + aacc[3][r];
#pragma unroll
    for (int m = 1; m <= 8; m <<= 1)
#pragma unroll
      for (int r = 0; r < 4; ++r) denA[r] += __shfl_xor(denA[r], m);
    // As transpose (in-wave)
#pragma unroll
    for (int ct = 0; ct < 4; ++ct)
#pragma unroll
      for (int r = 0; r < 4; ++r)
        As[w * 16 + hl * 4 + r][ct * 16 + ll] = f2bs(aacc[ct][r]);
    const bf16x8 aa0 = *(const bf16x8*)&As[w * 16 + ll][hl * 8];
    const bf16x8 aa1 = *(const bf16x8*)&As[w * 16 + ll][32 + hl * 8];

    // num = Q Sprev + A V  (Sprev^T, V^T fragments from global)
    const unsigned short* sp = mir + sblk * 4096;
    const unsigned short* vg = vtg + sblk * 4096;
    f32x4 nacc[4];
#pragma unroll
    for (int ct = 0; ct < 4; ++ct) {
      bf16x8 s0 = *(const bf16x8*)(sp + (ct * 16 + ll) * 64 + hl * 8);
      bf16x8 s1 = *(const bf16x8*)(sp + (ct * 16 + ll) * 64 + 32 + hl * 8);
      f32x4 a = zero4(); a = MFMA(qa0, s0, a); a = MFMA(qa1, s1, a);
      bf16x8 v0 = *(const bf16x8*)(vg + (ct * 16 + ll) * 64 + hl * 8);
      a = MFMA(aa0, v0, a);
      if (w >= 2) {    // rows t>=32: s in [32,64) can be nonzero
        bf16x8 v1 = *(const bf16x8*)(vg + (ct * 16 + ll) * 64 + 32 + hl * 8);
        a = MFMA(aa1, v1, a);
      }
      nacc[ct] = a;
    }
    float inv[4];
#pragma unroll
    for (int r = 0; r < 4; ++r)
      inv[r] = 1.f / (den0[r] + denA[r] + 1e-6f);
    // ys transpose (in-wave)
#pragma unroll
    for (int ct = 0; ct < 4; ++ct)
#pragma unroll
      for (int r = 0; r < 4; ++r)
        ys[w * 16 + hl * 4 + r][ct * 16 + ll] = f2bs(nacc[ct][r] * inv[r]);
    const bf16x8 ya0 = *(const bf16x8*)&ys[w * 16 + ll][hl * 8];
    const bf16x8 ya1 = *(const bf16x8*)&ys[w * 16 + ll][32 + hl * 8];

    // out accumulation: oacc += y_h @ Wp_h
#pragma unroll
    for (int ct = 0; ct < 4; ++ct) {
      bf16x8 wb0 = *(const bf16x8*)(wpT + (size_t)(ct * 16 + ll) * 1024 + h * 64 + hl * 8);
      bf16x8 wb1 = *(const bf16x8*)(wpT + (size_t)(ct * 16 + ll) * 1024 + h * 64 + 32 + hl * 8);
      oacc[ct] = MFMA(ya0, wb0, oacc[ct]);
      oacc[ct] = MFMA(ya1, wb1, oacc[ct]);
    }
  }

  float* pp = partial + ((size_t)g * (Bv * Sv) + (size_t)(b * Sv + c * 64)) * 64;
#pragma unroll
  for (int ct = 0; ct < 4; ++ct)
#pragma unroll
    for (int r = 0; r < 4; ++r)
      pp[(size_t)(w * 16 + hl * 4 + r) * 64 + ct * 16 + ll] = oacc[ct][r];
}

// ---------------------------------------------------------------------------
// K4: out = p0 + p1 + p2 + p3
// ---------------------------------------------------------------------------
__global__ __launch_bounds__(256) void k_add(
    const float* __restrict__ partial, float* __restrict__ out)
{
  const int idx = blockIdx.x * 256 + threadIdx.x;   // float4 index
  const float4* p = (const float4*)partial;
  float4 a = p[idx];
  float4 b = p[idx + 262144];
  float4 c = p[idx + 524288];
  float4 d = p[idx + 786432];
  float4 r;
  r.x = a.x + b.x + c.x + d.x;
  r.y = a.y + b.y + c.y + d.y;
  r.z = a.z + b.z + c.z + d.z;
  r.w = a.w + b.w + c.w + d.w;
  ((float4*)out)[idx] = r;
}

// ---------------------------------------------------------------------------
extern "C" void kernel_launch(void* const* d_in, const int* in_sizes, int n_in,
                              void* d_out, int out_size, void* d_ws, size_t ws_size,
                              hipStream_t stream)
{
  const float* x  = (const float*)d_in[0];
  const float* Wq = (const float*)d_in[1];
  const float* Wk = (const float*)d_in[2];
  const float* Wv = (const float*)d_in[3];
  const float* Wp = (const float*)d_in[4];
  float* out = (float*)d_out;

  // ws layout (bytes):
  //   mir    bf16 [4096][4096]   33.55 MB
  //   zmir   f32  [4096][64]      1.05 MB
  //   krow_g bf16 [4096][4096]   33.55 MB
  //   vtg    bf16 [4096][4096]   33.55 MB
  //   wqT/wkT/wvT bf16 64K each, wpT bf16 64K
  //   partial f32 [4][16384][64] 16.78 MB          total ~119 MB
  unsigned short* mir = (unsigned short*)d_ws;
  float* zmir = (float*)((char*)d_ws + 33554432);
  unsigned short* krow_g = (unsigned short*)((char*)d_ws + 34603008);
  unsigned short* vtg = krow_g + 16777216;
  unsigned short* wqT = vtg + 16777216;
  unsigned short* wkT = wqT + 65536;
  unsigned short* wvT = wkT + 65536;
  unsigned short* wpT = wvT + 65536;
  float* partial = (float*)(wpT + 65536);

  hipLaunchKernelGGL(k_prep_w, dim3(80), dim3(256), 0, stream,
                     Wq, Wk, Wv, Wp, wqT, wkT, wvT, wpT);
  hipLaunchKernelGGL(k_chunk_state, dim3(BHv * NCv), dim3(256), 0, stream,
                     x, wkT, wvT, mir, zmir, krow_g, vtg);
  hipLaunchKernelGGL(k_prefix, dim3(BHv * 17), dim3(256), 0, stream, mir, zmir);
  hipLaunchKernelGGL(k_out, dim3(Bv * NCv * 4), dim3(256), 0, stream,
                     x, wqT, krow_g, vtg, mir, zmir, wpT, partial);
  hipLaunchKernelGGL(k_add, dim3(1024), dim3(256), 0, stream, partial, out);
}

// Round 5
// 150.893 us; speedup vs baseline: 9.5155x; 1.0500x over previous
//
#include <hip/hip_runtime.h>
#include <hip/hip_bf16.h>

// Problem constants
#define Bv 4
#define Sv 4096
#define Dv 1024
#define Hv 16
#define Ov 64
#define NCv 64
#define BHv 64

typedef __attribute__((ext_vector_type(8))) short bf16x8;
typedef __attribute__((ext_vector_type(4))) unsigned short u16x4;
typedef __attribute__((ext_vector_type(8))) unsigned short u16x8;
typedef __attribute__((ext_vector_type(4))) float f32x4;
#define MFMA(a, b, c) __builtin_amdgcn_mfma_f32_16x16x32_bf16(a, b, c, 0, 0, 0)

__device__ __forceinline__ unsigned short f2bs(float f) {
  union { __hip_bfloat16 h; unsigned short u; } v;
  v.h = __float2bfloat16(f);
  return v.u;
}
__device__ __forceinline__ float b2f(unsigned short u) {
  union { unsigned u; float f; } v; v.u = ((unsigned)u) << 16; return v.f;
}
__device__ __forceinline__ float elu1(float a) {
  return a > 0.f ? a + 1.f : expf(a);
}
__device__ __forceinline__ f32x4 zero4() {
  f32x4 v = {0.f, 0.f, 0.f, 0.f}; return v;
}
__device__ __forceinline__ bf16x8 pack8(float4 a, float4 b) {
  union { u16x8 u; bf16x8 h; } r;
  r.u[0] = f2bs(a.x); r.u[1] = f2bs(a.y); r.u[2] = f2bs(a.z); r.u[3] = f2bs(a.w);
  r.u[4] = f2bs(b.x); r.u[5] = f2bs(b.y); r.u[6] = f2bs(b.z); r.u[7] = f2bs(b.w);
  return r.h;
}

// ---------------------------------------------------------------------------
// K0 prep: Wq/Wk/Wv [h][d][o] -> bf16 [h][o][d]; Wp [d][o2] -> bf16 [o2][d]
// ---------------------------------------------------------------------------
__global__ __launch_bounds__(256) void k_prep_w(
    const float* __restrict__ Wq, const float* __restrict__ Wk,
    const float* __restrict__ Wv, const float* __restrict__ Wp,
    unsigned short* __restrict__ wqT, unsigned short* __restrict__ wkT,
    unsigned short* __restrict__ wvT, unsigned short* __restrict__ wpT)
{
  const int blk = blockIdx.x, tid = threadIdx.x;
  if (blk < 16) {
    int h = blk;
    for (int j = tid; j < 4096; j += 256) {       // j = o*64 + d (output idx)
      int o = j >> 6, d = j & 63;
      int src = h * 4096 + d * 64 + o;
      wqT[h * 4096 + j] = f2bs(Wq[src]);
      wkT[h * 4096 + j] = f2bs(Wk[src]);
      wvT[h * 4096 + j] = f2bs(Wv[src]);
    }
  } else {
    int b2 = blk - 16;
#pragma unroll
    for (int k = 0; k < 4; ++k) {
      int j = b2 * 1024 + tid + k * 256;          // j = o2*1024 + d
      int o = j >> 10, d = j & 1023;
      wpT[j] = f2bs(Wp[d * 64 + o]);
    }
  }
}

// ---------------------------------------------------------------------------
// K1: per (bh,chunk): K=elu1(x Wk), V=x Wv
//   publishes: kg [s][e] bf16 (direct frag stores), vg [o][t] bf16,
//              mir [o][e] = (K^T V)^T bf16, zmir [e] f32
// LDS: kT 9216 + vT 9216 + zpart 1024 = 19.5 KB -> 8 blocks/CU
// ---------------------------------------------------------------------------
__global__ __launch_bounds__(256) void k_chunk_state(
    const float* __restrict__ x, const unsigned short* __restrict__ wkT,
    const unsigned short* __restrict__ wvT, unsigned short* __restrict__ mir,
    float* __restrict__ zmir, unsigned short* __restrict__ krow_g,
    unsigned short* __restrict__ vtg)
{
  __shared__ __align__(16) unsigned short kT[64][72];     // K^T[e][t]
  __shared__ __align__(16) unsigned short vT[64][72];     // V^T[o][t]
  __shared__ float zpart[4][64];

  const int tid = threadIdx.x, blk = blockIdx.x;
  const int c = blk & 63, bh = blk >> 6, h = bh & 15, b = bh >> 4;
  const int lane = tid & 63, w = tid >> 6;
  const int ll = lane & 15, hl = lane >> 4;

  // x fragment (f32 -> bf16 in-register)
  const float* xr = x + ((size_t)(b * Sv + c * 64 + w * 16 + ll)) * 1024 + h * 64;
  float4 f0 = *(const float4*)(xr + hl * 8);
  float4 f1 = *(const float4*)(xr + hl * 8 + 4);
  float4 f2 = *(const float4*)(xr + 32 + hl * 8);
  float4 f3 = *(const float4*)(xr + 32 + hl * 8 + 4);
  const bf16x8 xa0 = pack8(f0, f1);
  const bf16x8 xa1 = pack8(f2, f3);

  unsigned short* kg = krow_g + (size_t)blk * 4096;

  // K = elu1(x Wk) -> kT LDS + kg global + zpart
  const unsigned short* wk = wkT + h * 4096;
#pragma unroll
  for (int ct = 0; ct < 4; ++ct) {
    bf16x8 b0 = *(const bf16x8*)(wk + (ct * 16 + ll) * 64 + hl * 8);
    bf16x8 b1 = *(const bf16x8*)(wk + (ct * 16 + ll) * 64 + 32 + hl * 8);
    f32x4 a = zero4(); a = MFMA(xa0, b0, a); a = MFMA(xa1, b1, a);
    u16x4 p; float part = 0.f;
#pragma unroll
    for (int r = 0; r < 4; ++r) {
      float kv = elu1(a[r]); part += kv;
      p[r] = f2bs(kv);
      kg[(w * 16 + hl * 4 + r) * 64 + ct * 16 + ll] = p[r];
    }
    *(u16x4*)&kT[ct * 16 + ll][w * 16 + hl * 4] = p;
    part += __shfl_xor(part, 16);
    part += __shfl_xor(part, 32);
    if (hl == 0) zpart[w][ct * 16 + ll] = part;
  }
  // V = x Wv -> vT[o][t]
  const unsigned short* wv = wvT + h * 4096;
#pragma unroll
  for (int ct = 0; ct < 4; ++ct) {
    bf16x8 b0 = *(const bf16x8*)(wv + (ct * 16 + ll) * 64 + hl * 8);
    bf16x8 b1 = *(const bf16x8*)(wv + (ct * 16 + ll) * 64 + 32 + hl * 8);
    f32x4 a = zero4(); a = MFMA(xa0, b0, a); a = MFMA(xa1, b1, a);
    u16x4 p;
#pragma unroll
    for (int r = 0; r < 4; ++r) p[r] = f2bs(a[r]);
    *(u16x4*)&vT[ct * 16 + ll][w * 16 + hl * 4] = p;
  }
  __syncthreads();

  // KtV: C[e][o]; write transposed [o][e] to mir
  const bf16x8 ka0 = *(const bf16x8*)&kT[w * 16 + ll][hl * 8];
  const bf16x8 ka1 = *(const bf16x8*)&kT[w * 16 + ll][32 + hl * 8];
  unsigned short* mp = mir + (size_t)blk * 4096;
#pragma unroll
  for (int ct = 0; ct < 4; ++ct) {
    bf16x8 v0 = *(const bf16x8*)&vT[ct * 16 + ll][hl * 8];
    bf16x8 v1 = *(const bf16x8*)&vT[ct * 16 + ll][32 + hl * 8];
    f32x4 s = zero4(); s = MFMA(ka0, v0, s); s = MFMA(ka1, v1, s);
    u16x4 p;
#pragma unroll
    for (int r = 0; r < 4; ++r) p[r] = f2bs(s[r]);
    *(u16x4*)&mp[(ct * 16 + ll) * 64 + w * 16 + hl * 4] = p;
  }
  // coalesced publish of vT
  unsigned short* vg = vtg + (size_t)blk * 4096;
#pragma unroll
  for (int it = 0; it < 2; ++it) {
    int j = tid * 8 + it * 2048;
    int r = j >> 6, col = j & 63;
    *(uint4*)&vg[j] = *(const uint4*)&vT[r][col];
  }
  if (tid < 64)
    zmir[(size_t)blk * 64 + tid] =
        zpart[0][tid] + zpart[1][tid] + zpart[2][tid] + zpart[3][tid];
}

// ---------------------------------------------------------------------------
// K2: exclusive prefix over chunks — all 64 loads issued up-front into regs,
// register-resident scan, then 64 stores. grid = 64 bh * 17 groups.
// ---------------------------------------------------------------------------
__global__ __launch_bounds__(256) void k_prefix(
    unsigned short* __restrict__ mir, float* __restrict__ zmir)
{
  const int bh = blockIdx.x / 17, g = blockIdx.x % 17;
  const int tid = threadIdx.x;
  if (g < 16) {
    size_t base = (size_t)bh * 64 * 4096 + g * 256 + tid;
    unsigned short v[64];
#pragma unroll
    for (int cc = 0; cc < 64; ++cc) v[cc] = mir[base + (size_t)cc * 4096];
    float carry = 0.f;
#pragma unroll
    for (int cc = 0; cc < 64; ++cc) {
      float f = b2f(v[cc]);
      v[cc] = f2bs(carry);
      carry += f;
    }
#pragma unroll
    for (int cc = 0; cc < 64; ++cc) mir[base + (size_t)cc * 4096] = v[cc];
  } else if (tid < 64) {
    size_t base = (size_t)bh * 64 * 64 + tid;
    float v[64];
#pragma unroll
    for (int cc = 0; cc < 64; ++cc) v[cc] = zmir[base + (size_t)cc * 64];
    float carry = 0.f;
#pragma unroll
    for (int cc = 0; cc < 64; ++cc) {
      float f = v[cc];
      v[cc] = carry;
      carry += f;
    }
#pragma unroll
    for (int cc = 0; cc < 64; ++cc) zmir[base + (size_t)cc * 64] = v[cc];
  }
}

// ---------------------------------------------------------------------------
// K3: per (b,chunk,head-pair): for 2 heads:
//   Q = elu1(x Wq);  A = tril(Q K^T);  y_h = (Q Sprev + A V) / den
//   oacc += y_h @ Wp_h      -> partial[g] (bf16)
// Barrier-free; ONE wave-private-striped LDS buffer reused qs->As->ys->store.
// ---------------------------------------------------------------------------
__global__ __launch_bounds__(256) void k_out(
    const float* __restrict__ x, const unsigned short* __restrict__ wqT,
    const unsigned short* __restrict__ krow_g, const unsigned short* __restrict__ vtg,
    const unsigned short* __restrict__ mir, const float* __restrict__ zmir,
    const unsigned short* __restrict__ wpT, unsigned short* __restrict__ partial)
{
  __shared__ __align__(16) unsigned short ts[64][72];

  const int tid = threadIdx.x, bid = blockIdx.x;
  const int g = bid & 7, c = (bid >> 3) & 63, b = bid >> 9;
  const int lane = tid & 63, w = tid >> 6;
  const int ll = lane & 15, hl = lane >> 4;

  f32x4 oacc[4] = {zero4(), zero4(), zero4(), zero4()};

#pragma unroll 1
  for (int hi = 0; hi < 2; ++hi) {
    const int h = g * 2 + hi;
    const size_t sblk = (size_t)((b * 16 + h) * 64 + c);

    // x fragment
    const float* xr = x + ((size_t)(b * Sv + c * 64 + w * 16 + ll)) * 1024 + h * 64;
    float4 f0 = *(const float4*)(xr + hl * 8);
    float4 f1 = *(const float4*)(xr + hl * 8 + 4);
    float4 f2 = *(const float4*)(xr + 32 + hl * 8);
    float4 f3 = *(const float4*)(xr + 32 + hl * 8 + 4);
    const bf16x8 xa0 = pack8(f0, f1);
    const bf16x8 xa1 = pack8(f2, f3);

    // Q projection
    const unsigned short* wq = wqT + h * 4096;
    f32x4 qacc[4];
#pragma unroll
    for (int ct = 0; ct < 4; ++ct) {
      bf16x8 b0 = *(const bf16x8*)(wq + (ct * 16 + ll) * 64 + hl * 8);
      bf16x8 b1 = *(const bf16x8*)(wq + (ct * 16 + ll) * 64 + 32 + hl * 8);
      f32x4 a = zero4(); a = MFMA(xa0, b0, a); a = MFMA(xa1, b1, a);
      qacc[ct] = a;
    }
    // elu + den0 = q . zprev + qs transpose (ts as qs)
    const float* zp = zmir + sblk * 64;
    float den0[4] = {0.f, 0.f, 0.f, 0.f};
#pragma unroll
    for (int ct = 0; ct < 4; ++ct) {
      float zv = zp[ct * 16 + ll];
#pragma unroll
      for (int r = 0; r < 4; ++r) {
        float q = elu1(qacc[ct][r]);
        den0[r] += q * zv;
        ts[w * 16 + hl * 4 + r][ct * 16 + ll] = f2bs(q);
      }
    }
#pragma unroll
    for (int m = 1; m <= 8; m <<= 1)
#pragma unroll
      for (int r = 0; r < 4; ++r) den0[r] += __shfl_xor(den0[r], m);

    const bf16x8 qa0 = *(const bf16x8*)&ts[w * 16 + ll][hl * 8];
    const bf16x8 qa1 = *(const bf16x8*)&ts[w * 16 + ll][32 + hl * 8];

    // A = tril(Q K^T)  (K fragments from global)
    const unsigned short* kg = krow_g + sblk * 4096;
    f32x4 aacc[4];
#pragma unroll
    for (int ct = 0; ct < 4; ++ct) {
      if (ct <= w) {   // wave-uniform
        bf16x8 b0 = *(const bf16x8*)(kg + (ct * 16 + ll) * 64 + hl * 8);
        bf16x8 b1 = *(const bf16x8*)(kg + (ct * 16 + ll) * 64 + 32 + hl * 8);
        f32x4 a = zero4(); a = MFMA(qa0, b0, a); a = MFMA(qa1, b1, a);
        if (ct == w) {  // causal mask on diagonal tile (static indices)
#pragma unroll
          for (int r = 0; r < 4; ++r)
            if (ll > hl * 4 + r) a[r] = 0.f;
        }
        aacc[ct] = a;
      } else {
        aacc[ct] = zero4();
      }
    }
    // rowsum(A)
    float denA[4];
#pragma unroll
    for (int r = 0; r < 4; ++r)
      denA[r] = aacc[0][r] + aacc[1][r] + aacc[2][r] + aacc[3][r];
#pragma unroll
    for (int m = 1; m <= 8; m <<= 1)
#pragma unroll
      for (int r = 0; r < 4; ++r) denA[r] += __shfl_xor(denA[r], m);
    // As transpose (ts as As; qa already in regs)
#pragma unroll
    for (int ct = 0; ct < 4; ++ct)
#pragma unroll
      for (int r = 0; r < 4; ++r)
        ts[w * 16 + hl * 4 + r][ct * 16 + ll] = f2bs(aacc[ct][r]);
    const bf16x8 aa0 = *(const bf16x8*)&ts[w * 16 + ll][hl * 8];
    const bf16x8 aa1 = *(const bf16x8*)&ts[w * 16 + ll][32 + hl * 8];

    // num = Q Sprev + A V  (Sprev^T, V^T fragments from global)
    const unsigned short* sp = mir + sblk * 4096;
    const unsigned short* vg = vtg + sblk * 4096;
    f32x4 nacc[4];
#pragma unroll
    for (int ct = 0; ct < 4; ++ct) {
      bf16x8 s0 = *(const bf16x8*)(sp + (ct * 16 + ll) * 64 + hl * 8);
      bf16x8 s1 = *(const bf16x8*)(sp + (ct * 16 + ll) * 64 + 32 + hl * 8);
      f32x4 a = zero4(); a = MFMA(qa0, s0, a); a = MFMA(qa1, s1, a);
      bf16x8 v0 = *(const bf16x8*)(vg + (ct * 16 + ll) * 64 + hl * 8);
      a = MFMA(aa0, v0, a);
      if (w >= 2) {    // rows t>=32: s in [32,64) can be nonzero
        bf16x8 v1 = *(const bf16x8*)(vg + (ct * 16 + ll) * 64 + 32 + hl * 8);
        a = MFMA(aa1, v1, a);
      }
      nacc[ct] = a;
    }
    float inv[4];
#pragma unroll
    for (int r = 0; r < 4; ++r)
      inv[r] = 1.f / (den0[r] + denA[r] + 1e-6f);
    // ys transpose (ts as ys; aa already in regs)
#pragma unroll
    for (int ct = 0; ct < 4; ++ct)
#pragma unroll
      for (int r = 0; r < 4; ++r)
        ts[w * 16 + hl * 4 + r][ct * 16 + ll] = f2bs(nacc[ct][r] * inv[r]);
    const bf16x8 ya0 = *(const bf16x8*)&ts[w * 16 + ll][hl * 8];
    const bf16x8 ya1 = *(const bf16x8*)&ts[w * 16 + ll][32 + hl * 8];

    // out accumulation: oacc += y_h @ Wp_h
#pragma unroll
    for (int ct = 0; ct < 4; ++ct) {
      bf16x8 wb0 = *(const bf16x8*)(wpT + (size_t)(ct * 16 + ll) * 1024 + h * 64 + hl * 8);
      bf16x8 wb1 = *(const bf16x8*)(wpT + (size_t)(ct * 16 + ll) * 1024 + h * 64 + 32 + hl * 8);
      oacc[ct] = MFMA(ya0, wb0, oacc[ct]);
      oacc[ct] = MFMA(ya1, wb1, oacc[ct]);
    }
  }

  // coalesced bf16 partial store via ts (wave-private rows; no barrier)
#pragma unroll
  for (int ct = 0; ct < 4; ++ct)
#pragma unroll
    for (int r = 0; r < 4; ++r)
      ts[w * 16 + hl * 4 + r][ct * 16 + ll] = f2bs(oacc[ct][r]);
  unsigned short* pp = partial + (size_t)g * 1048576 +
                       ((size_t)(b * Sv + c * 64)) * 64;
  {
    int r_ = tid >> 2, c_ = (tid & 3) * 16;   // wave w covers rows w*16..w*16+15
    uint4 a0 = *(const uint4*)&ts[r_][c_];
    uint4 a1 = *(const uint4*)&ts[r_][c_ + 8];
    *(uint4*)&pp[r_ * 64 + c_] = a0;
    *(uint4*)&pp[r_ * 64 + c_ + 8] = a1;
  }
}

// ---------------------------------------------------------------------------
// K4: out = sum_g partial[g]  (bf16 -> f32)
// ---------------------------------------------------------------------------
__global__ __launch_bounds__(256) void k_add(
    const unsigned short* __restrict__ partial, float* __restrict__ out)
{
  const int idx = (blockIdx.x * 256 + threadIdx.x) * 8;
  float acc[8] = {0.f, 0.f, 0.f, 0.f, 0.f, 0.f, 0.f, 0.f};
#pragma unroll
  for (int g = 0; g < 8; ++g) {
    u16x8 p = *(const u16x8*)(partial + (size_t)g * 1048576 + idx);
#pragma unroll
    for (int j = 0; j < 8; ++j) acc[j] += b2f(p[j]);
  }
  float4 r0 = {acc[0], acc[1], acc[2], acc[3]};
  float4 r1 = {acc[4], acc[5], acc[6], acc[7]};
  *(float4*)(out + idx) = r0;
  *(float4*)(out + idx + 4) = r1;
}

// ---------------------------------------------------------------------------
extern "C" void kernel_launch(void* const* d_in, const int* in_sizes, int n_in,
                              void* d_out, int out_size, void* d_ws, size_t ws_size,
                              hipStream_t stream)
{
  const float* x  = (const float*)d_in[0];
  const float* Wq = (const float*)d_in[1];
  const float* Wk = (const float*)d_in[2];
  const float* Wv = (const float*)d_in[3];
  const float* Wp = (const float*)d_in[4];
  float* out = (float*)d_out;

  // ws layout (bytes):
  //   mir    bf16 [4096][4096]   33.55 MB
  //   zmir   f32  [4096][64]      1.05 MB
  //   kg     bf16 [4096][4096]   33.55 MB
  //   vg     bf16 [4096][4096]   33.55 MB
  //   wqT/wkT/wvT/wpT bf16 128 KB each
  //   partial bf16 [8][16384][64] 16.78 MB         total ~119 MB
  unsigned short* mir = (unsigned short*)d_ws;
  float* zmir = (float*)((char*)d_ws + 33554432);
  unsigned short* krow_g = (unsigned short*)((char*)d_ws + 34603008);
  unsigned short* vtg = krow_g + 16777216;
  unsigned short* wqT = vtg + 16777216;
  unsigned short* wkT = wqT + 65536;
  unsigned short* wvT = wkT + 65536;
  unsigned short* wpT = wvT + 65536;
  unsigned short* partial = wpT + 65536;

  hipLaunchKernelGGL(k_prep_w, dim3(80), dim3(256), 0, stream,
                     Wq, Wk, Wv, Wp, wqT, wkT, wvT, wpT);
  hipLaunchKernelGGL(k_chunk_state, dim3(BHv * NCv), dim3(256), 0, stream,
                     x, wkT, wvT, mir, zmir, krow_g, vtg);
  hipLaunchKernelGGL(k_prefix, dim3(BHv * 17), dim3(256), 0, stream, mir, zmir);
  hipLaunchKernelGGL(k_out, dim3(Bv * NCv * 8), dim3(256), 0, stream,
                     x, wqT, krow_g, vtg, mir, zmir, wpT, partial);
  hipLaunchKernelGGL(k_add, dim3(512), dim3(256), 0, stream, partial, out);
}